// Round 1
// baseline (500.519 us; speedup 1.0000x reference)
//
#include <hip/hip_runtime.h>
#include <cstdint>
#include <cmath>

#define S_LEN 4096
#define B_N   16
#define C_N   512
#define CM1   511
#define T_M   512

// ws layout (float elements)
#define OFF_ALPHA 0         // [B][S]   sigmoid, later overwritten with scaled alpha
#define OFF_LW    65536     // [B][S]
#define OFF_RW    131072    // [B][S]
#define OFF_ASUM  196608    // [B]
#define OFF_DEST  196640    // int[B][S+1] = 16*4097 ints
#define OFF_FEATS 262208    // [8192][512] fp32 (k=511 zero-padded)

// ---------------- K1: alpha = sigmoid(masked last channel) ----------------
__global__ void k_alpha(const float* __restrict__ x, const uint8_t* __restrict__ mask,
                        float* __restrict__ ws) {
    int b  = blockIdx.y;
    int s0 = blockIdx.x * 512;
    float* alpha = ws + OFF_ALPHA;
    for (int i = threadIdx.x; i < 512; i += 256) {
        int s = s0 + i;
        float a = x[((size_t)s * B_N + b) * C_N + CM1];
        if (mask[(size_t)b * S_LEN + s]) a = -10000.0f;
        float al = 1.0f / (1.0f + expf(-a));   // precise expf (matches np to ~1 ulp)
        alpha[(size_t)b * S_LEN + s] = al;
    }
}

// ---------------- K2: alpha_sum via numpy pairwise replication ----------------
__global__ void k_sum(float* __restrict__ ws, float* __restrict__ out_asum) {
    int b = blockIdx.x;
    const float* alpha = ws + OFF_ALPHA + (size_t)b * S_LEN;
    __shared__ float sblk[32];
    int j = threadIdx.x;
    if (j < 32) {
        // numpy pairwise base case, n=128: 8 accumulators stride-8
        const float* a = alpha + j * 128;
        float r0 = a[0], r1 = a[1], r2 = a[2], r3 = a[3];
        float r4 = a[4], r5 = a[5], r6 = a[6], r7 = a[7];
        for (int i = 8; i < 128; i += 8) {
            r0 += a[i + 0]; r1 += a[i + 1]; r2 += a[i + 2]; r3 += a[i + 3];
            r4 += a[i + 4]; r5 += a[i + 5]; r6 += a[i + 6]; r7 += a[i + 7];
        }
        sblk[j] = ((r0 + r1) + (r2 + r3)) + ((r4 + r5) + (r6 + r7));
    }
    __syncthreads();
    if (j == 0) {
        // perfect binary tree over 32 leaves (numpy's recursive halving, 4096=2^12)
        float v[32];
        for (int i = 0; i < 32; ++i) v[i] = sblk[i];
        for (int n = 32; n > 1; n >>= 1)
            for (int i = 0; i < (n >> 1); ++i) v[i] = v[2 * i] + v[2 * i + 1];
        ws[OFF_ASUM + b] = v[0];
        out_asum[b] = v[0];
    }
}

// ---------------- K3: alpha *= BETA * tl / alpha_sum (IEEE div) ----------------
__global__ void k_scale(float* __restrict__ ws, const int* __restrict__ tl) {
    int b = blockIdx.y;
    float tlf  = (float)tl[b];
    float asum = ws[OFF_ASUM + b];
    float* alpha = ws + OFF_ALPHA + (size_t)b * S_LEN + blockIdx.x * 512;
    for (int i = threadIdx.x; i < 512; i += 256) {
        float al = alpha[i];
        float v  = (al * tlf) / asum;   // (alpha*BETA)*tlf / asum, BETA=1 exact
        alpha[i] = v;
    }
}

// ---------------- K4: sequential fp32 scan -> dest/left_w/right_w ----------------
__global__ void k_scan(float* __restrict__ ws) {
    __shared__ float buf[16 * 516];    // stride 516: 16B-aligned lanes, 2-way bank alias (free)
    float* alpha = ws + OFF_ALPHA;
    float* lw    = ws + OFF_LW;
    float* rw    = ws + OFF_RW;
    int*   dest  = (int*)(ws + OFF_DEST);
    int tid = threadIdx.x;
    float c = 0.0f;
    int dprev = 0;
    if (tid < 16) dest[tid * 4097] = 0;
    for (int c0 = 0; c0 < S_LEN; c0 += 512) {
        __syncthreads();
        for (int idx = tid; idx < 16 * 512; idx += 256) {
            int bb = idx >> 9, i = idx & 511;
            buf[bb * 516 + i] = alpha[(size_t)bb * S_LEN + c0 + i];
        }
        __syncthreads();
        if (tid < 16) {
            int b = tid;
            for (int i = 0; i < 512; i += 4) {
                float4 v = *(const float4*)&buf[b * 516 + i];
                float vv[4] = {v.x, v.y, v.z, v.w};
                #pragma unroll
                for (int q = 0; q < 4; ++q) {
                    float as_ = vv[q];
                    c = c + as_;                          // np.cumsum: strictly sequential
                    int dn   = (int)floorf(c + 1e-4f);    // floor(csum/BETA + 0.0001)
                    int fire = dn - dprev;
                    float rwv = (fire > 0) ? (c - (float)dn) : as_;
                    float ex  = (fire > 1) ? (float)(fire - 1) : 0.0f;
                    float lwv = (as_ - rwv) - ex;
                    int s = c0 + i + q;
                    dest[b * 4097 + s + 1] = dn;
                    lw[(size_t)b * S_LEN + s] = lwv;
                    rw[(size_t)b * S_LEN + s] = rwv;
                    dprev = dn;
                }
            }
        }
    }
}

// ---------------- K5: gather feats[b,t,:] = sum_s w(s,t) * x[s,b,0:511] ----------------
__global__ void k_gather(const float* __restrict__ x, float* __restrict__ ws) {
    int t = blockIdx.x;
    int b = blockIdx.y;
    const int*   db = (const int*)(ws + OFF_DEST) + b * 4097;
    const float* lw = ws + OFF_LW + (size_t)b * S_LEN;
    const float* rw = ws + OFF_RW + (size_t)b * S_LEN;
    int tid = threadIdx.x;
    // s_hi: last s in [0,4095] with db[s] <= t  (db[0]=0 so lo>=1 always)
    int lo = 0, hi = 4097;
    while (lo < hi) {
        int mid = (lo + hi) >> 1;
        int v = (mid <= 4096) ? db[mid] : 0x7fffffff;
        if (v > t) hi = mid; else lo = mid + 1;
    }
    int s_hi = lo - 1; if (s_hi > 4095) s_hi = 4095;
    // s_lo: first s with db[s+1] >= t
    lo = 1; hi = 4097;
    while (lo < hi) {
        int mid = (lo + hi) >> 1;
        int v = (mid <= 4096) ? db[mid] : 0x7fffffff;
        if (v >= t) hi = mid; else lo = mid + 1;
    }
    int s_lo = lo - 1;                      // lo==4097 -> s_lo=4096 > s_hi -> empty row
    float2 acc = make_float2(0.0f, 0.0f);
    const float2* x2 = (const float2*)x;
    for (int s = s_lo; s <= s_hi; ++s) {
        int ds = db[s], dn = db[s + 1];
        float w;
        if (t == ds)      w = (t == dn) ? (lw[s] + rw[s]) : lw[s];
        else              w = (t == dn) ? rw[s] : 1.0f;   // interior row: BETA
        float2 xv = x2[((size_t)s * B_N + b) * 256 + tid];
        acc.x += w * xv.x;
        acc.y += w * xv.y;
    }
    if (tid == 255) acc.y = 0.0f;           // channel 511 excluded (K zero-pad)
    float* feats = ws + OFF_FEATS;
    *(float2*)&feats[(size_t)(b * T_M + t) * 512 + tid * 2] = acc;
}

// ---------------- K6: out[t,b,:] = feats[b,t,:] @ W^T + b_out (fp32 vector GEMM) ----------------
#define ASTR 68
__global__ __launch_bounds__(256) void k_gemm(const float* __restrict__ ws,
                                              const float* __restrict__ W,
                                              const float* __restrict__ bo,
                                              float* __restrict__ out) {
    __shared__ float As[16 * ASTR];
    __shared__ float Bs[16 * ASTR];
    const float* feats = ws + OFF_FEATS;
    int rbase = blockIdx.x * 64;
    int cbase = blockIdx.y * 64;
    int tid = threadIdx.x;
    int m4 = tid >> 2;          // 0..63
    int kq = tid & 3;           // 0..3
    int tx = tid & 15, ty = tid >> 4;
    float acc[4][4] = {};
    for (int kb = 0; kb < 512; kb += 16) {
        float4 av = *(const float4*)&feats[(size_t)(rbase + m4) * 512 + kb + kq * 4];
        float bv[4];
        #pragma unroll
        for (int j = 0; j < 4; ++j) {
            int kk = kb + kq * 4 + j;
            bv[j] = (kk < CM1) ? W[(size_t)(cbase + m4) * CM1 + kk] : 0.0f;
        }
        __syncthreads();
        As[(kq * 4 + 0) * ASTR + m4] = av.x;
        As[(kq * 4 + 1) * ASTR + m4] = av.y;
        As[(kq * 4 + 2) * ASTR + m4] = av.z;
        As[(kq * 4 + 3) * ASTR + m4] = av.w;
        #pragma unroll
        for (int j = 0; j < 4; ++j) Bs[(kq * 4 + j) * ASTR + m4] = bv[j];
        __syncthreads();
        #pragma unroll
        for (int k = 0; k < 16; ++k) {
            float4 a4 = *(const float4*)&As[k * ASTR + ty * 4];
            float4 b4 = *(const float4*)&Bs[k * ASTR + tx * 4];
            float ar[4] = {a4.x, a4.y, a4.z, a4.w};
            float br[4] = {b4.x, b4.y, b4.z, b4.w};
            #pragma unroll
            for (int i = 0; i < 4; ++i)
                #pragma unroll
                for (int j = 0; j < 4; ++j)
                    acc[i][j] += ar[i] * br[j];
        }
    }
    int c0 = cbase + tx * 4;
    float b0 = bo[c0 + 0], b1 = bo[c0 + 1], b2 = bo[c0 + 2], b3 = bo[c0 + 3];
    #pragma unroll
    for (int i = 0; i < 4; ++i) {
        int r = rbase + ty * 4 + i;
        int t = r & 511, b = r >> 9;
        float4 o;
        o.x = acc[i][0] + b0;
        o.y = acc[i][1] + b1;
        o.z = acc[i][2] + b2;
        o.w = acc[i][3] + b3;
        *(float4*)&out[((size_t)t * B_N + b) * C_N + c0] = o;
    }
}

extern "C" void kernel_launch(void* const* d_in, const int* in_sizes, int n_in,
                              void* d_out, int out_size, void* d_ws, size_t ws_size,
                              hipStream_t stream) {
    const float*   x    = (const float*)d_in[0];
    const uint8_t* mask = (const uint8_t*)d_in[1];
    const int*     tl   = (const int*)d_in[2];
    const float*   W    = (const float*)d_in[3];
    const float*   bo   = (const float*)d_in[4];
    float* out = (float*)d_out;
    float* ws  = (float*)d_ws;

    k_alpha <<<dim3(8, 16), 256, 0, stream>>>(x, mask, ws);
    k_sum   <<<16, 64, 0, stream>>>(ws, out + (size_t)T_M * B_N * C_N);
    k_scale <<<dim3(8, 16), 256, 0, stream>>>(ws, tl);
    k_scan  <<<1, 256, 0, stream>>>(ws);
    k_gather<<<dim3(T_M, B_N), 256, 0, stream>>>(x, ws);
    k_gemm  <<<dim3(128, 8), 256, 0, stream>>>(ws, W, bo, out);
}

// Round 2
// 298.635 us; speedup vs baseline: 1.6760x; 1.6760x over previous
//
#include <hip/hip_runtime.h>
#include <cstdint>
#include <cmath>

#define S_LEN 4096
#define B_N   16
#define C_N   512
#define CM1   511
#define T_M   512

// ws layout (float elements)
#define OFF_LW    65536     // [B][S]
#define OFF_RW    131072    // [B][S]
#define OFF_DEST  196640    // int[B][S+1] = 16*4097 ints
#define OFF_FEATS 262208    // [8192][512] fp32 (k=511 zero-padded)

// ---------------- K_front: sigmoid + alpha_sum + scale + parallel scan -> lw/rw/dest ----
// 16 blocks (one per batch) x 256 threads, 16 elements per thread.
// Continuity argument: dest flips from scan-order rounding move O(1e-4) weight only.
// Cross-thread fire consistency: dprev for a thread's first element is floor() of the
// EXACT stored last-inclusive csum of the previous thread (via LDS), so the dn chain
// telescopes bitwise-consistently.
__global__ __launch_bounds__(256) void k_front(const float* __restrict__ x,
                                               const uint8_t* __restrict__ mask,
                                               const int* __restrict__ tl,
                                               float* __restrict__ ws,
                                               float* __restrict__ out_asum) {
    int b = blockIdx.x;
    int t = threadIdx.x;
    int lane = t & 63, wid = t >> 6;
    int s0 = t * 16;

    __shared__ float ssum[4];
    __shared__ float wsum[4];
    __shared__ float linc[256];

    // 1) sigmoid of masked last channel
    float a[16];
    #pragma unroll
    for (int i = 0; i < 16; ++i) {
        int s = s0 + i;
        float v = x[((size_t)s * B_N + b) * C_N + CM1];
        if (mask[(size_t)b * S_LEN + s]) v = -10000.0f;
        a[i] = 1.0f / (1.0f + expf(-v));
    }

    // 2) alpha_sum: local sequential sum + wave shfl_xor reduce + LDS combine
    float ls = 0.0f;
    #pragma unroll
    for (int i = 0; i < 16; ++i) ls += a[i];
    #pragma unroll
    for (int off = 32; off >= 1; off >>= 1) ls += __shfl_xor(ls, off, 64);
    if (lane == 0) ssum[wid] = ls;
    __syncthreads();
    float tot = (ssum[0] + ssum[1]) + (ssum[2] + ssum[3]);
    if (t == 0) out_asum[b] = tot;

    // 3) scale
    float tlf = (float)tl[b];
    #pragma unroll
    for (int i = 0; i < 16; ++i) a[i] = (a[i] * tlf) / tot;

    // 4) local inclusive prefix
    float p[16];
    float run = 0.0f;
    #pragma unroll
    for (int i = 0; i < 16; ++i) { run += a[i]; p[i] = run; }

    // 5) block exclusive scan of thread totals
    float sc = run;
    #pragma unroll
    for (int off = 1; off < 64; off <<= 1) {
        float v = __shfl_up(sc, off, 64);
        if (lane >= off) sc += v;
    }
    if (lane == 63) wsum[wid] = sc;
    __syncthreads();
    float woff = 0.0f;
    for (int w = 0; w < wid; ++w) woff += wsum[w];
    float excl = woff + (sc - run);        // exclusive prefix for this thread

    // 6) publish exact last-inclusive csum for cross-thread dprev consistency
    linc[t] = excl + p[15];
    __syncthreads();
    float dsrc = (t == 0) ? 0.0f : linc[t - 1];
    int dprev = (int)floorf(dsrc + 1e-4f);

    // 7) per-element dest / left_w / right_w
    float* lw   = ws + OFF_LW + (size_t)b * S_LEN;
    float* rw   = ws + OFF_RW + (size_t)b * S_LEN;
    int*   dest = (int*)(ws + OFF_DEST) + b * 4097;
    if (t == 0) dest[0] = 0;

    float lwv[16], rwv[16];
    int dnv[16];
    #pragma unroll
    for (int i = 0; i < 16; ++i) {
        float c  = excl + p[i];
        int   dn = (int)floorf(c + 1e-4f);
        int fire = dn - dprev;
        float rv = (fire > 0) ? (c - (float)dn) : a[i];
        float ex = (fire > 1) ? (float)(fire - 1) : 0.0f;
        lwv[i] = (a[i] - rv) - ex;
        rwv[i] = rv;
        dnv[i] = dn;
        dprev = dn;
    }
    #pragma unroll
    for (int q = 0; q < 4; ++q) {
        *(float4*)&lw[s0 + q * 4] = make_float4(lwv[q*4+0], lwv[q*4+1], lwv[q*4+2], lwv[q*4+3]);
        *(float4*)&rw[s0 + q * 4] = make_float4(rwv[q*4+0], rwv[q*4+1], rwv[q*4+2], rwv[q*4+3]);
    }
    #pragma unroll
    for (int i = 0; i < 16; ++i) dest[s0 + i + 1] = dnv[i];
}

// ---------------- K5: gather feats[b,t,:] = sum_s w(s,t) * x[s,b,0:511] ----------------
__global__ void k_gather(const float* __restrict__ x, float* __restrict__ ws) {
    int t = blockIdx.x;
    int b = blockIdx.y;
    const int*   db = (const int*)(ws + OFF_DEST) + b * 4097;
    const float* lw = ws + OFF_LW + (size_t)b * S_LEN;
    const float* rw = ws + OFF_RW + (size_t)b * S_LEN;
    int tid = threadIdx.x;
    // s_hi: last s in [0,4095] with db[s] <= t  (db[0]=0 so lo>=1 always)
    int lo = 0, hi = 4097;
    while (lo < hi) {
        int mid = (lo + hi) >> 1;
        int v = (mid <= 4096) ? db[mid] : 0x7fffffff;
        if (v > t) hi = mid; else lo = mid + 1;
    }
    int s_hi = lo - 1; if (s_hi > 4095) s_hi = 4095;
    // s_lo: first s with db[s+1] >= t
    lo = 1; hi = 4097;
    while (lo < hi) {
        int mid = (lo + hi) >> 1;
        int v = (mid <= 4096) ? db[mid] : 0x7fffffff;
        if (v >= t) hi = mid; else lo = mid + 1;
    }
    int s_lo = lo - 1;                      // lo==4097 -> s_lo=4096 > s_hi -> empty row
    float2 acc = make_float2(0.0f, 0.0f);
    const float2* x2 = (const float2*)x;
    for (int s = s_lo; s <= s_hi; ++s) {
        int ds = db[s], dn = db[s + 1];
        float w;
        if (t == ds)      w = (t == dn) ? (lw[s] + rw[s]) : lw[s];
        else              w = (t == dn) ? rw[s] : 1.0f;   // interior row: BETA
        float2 xv = x2[((size_t)s * B_N + b) * 256 + tid];
        acc.x += w * xv.x;
        acc.y += w * xv.y;
    }
    if (tid == 255) acc.y = 0.0f;           // channel 511 excluded (K zero-pad)
    float* feats = ws + OFF_FEATS;
    *(float2*)&feats[(size_t)(b * T_M + t) * 512 + tid * 2] = acc;
}

// ---------------- K6: out[t,b,:] = feats[b,t,:] @ W^T + b_out (fp32 vector GEMM) ----------------
#define ASTR 68
__global__ __launch_bounds__(256) void k_gemm(const float* __restrict__ ws,
                                              const float* __restrict__ W,
                                              const float* __restrict__ bo,
                                              float* __restrict__ out) {
    __shared__ float As[16 * ASTR];
    __shared__ float Bs[16 * ASTR];
    const float* feats = ws + OFF_FEATS;
    int rbase = blockIdx.x * 64;
    int cbase = blockIdx.y * 64;
    int tid = threadIdx.x;
    int m4 = tid >> 2;          // 0..63
    int kq = tid & 3;           // 0..3
    int tx = tid & 15, ty = tid >> 4;
    float acc[4][4] = {};
    for (int kb = 0; kb < 512; kb += 16) {
        float4 av = *(const float4*)&feats[(size_t)(rbase + m4) * 512 + kb + kq * 4];
        float bv[4];
        #pragma unroll
        for (int j = 0; j < 4; ++j) {
            int kk = kb + kq * 4 + j;
            bv[j] = (kk < CM1) ? W[(size_t)(cbase + m4) * CM1 + kk] : 0.0f;
        }
        __syncthreads();
        As[(kq * 4 + 0) * ASTR + m4] = av.x;
        As[(kq * 4 + 1) * ASTR + m4] = av.y;
        As[(kq * 4 + 2) * ASTR + m4] = av.z;
        As[(kq * 4 + 3) * ASTR + m4] = av.w;
        #pragma unroll
        for (int j = 0; j < 4; ++j) Bs[(kq * 4 + j) * ASTR + m4] = bv[j];
        __syncthreads();
        #pragma unroll
        for (int k = 0; k < 16; ++k) {
            float4 a4 = *(const float4*)&As[k * ASTR + ty * 4];
            float4 b4 = *(const float4*)&Bs[k * ASTR + tx * 4];
            float ar[4] = {a4.x, a4.y, a4.z, a4.w};
            float br[4] = {b4.x, b4.y, b4.z, b4.w};
            #pragma unroll
            for (int i = 0; i < 4; ++i)
                #pragma unroll
                for (int j = 0; j < 4; ++j)
                    acc[i][j] += ar[i] * br[j];
        }
    }
    int c0 = cbase + tx * 4;
    float b0 = bo[c0 + 0], b1 = bo[c0 + 1], b2 = bo[c0 + 2], b3 = bo[c0 + 3];
    #pragma unroll
    for (int i = 0; i < 4; ++i) {
        int r = rbase + ty * 4 + i;
        int t = r & 511, b = r >> 9;
        float4 o;
        o.x = acc[i][0] + b0;
        o.y = acc[i][1] + b1;
        o.z = acc[i][2] + b2;
        o.w = acc[i][3] + b3;
        *(float4*)&out[((size_t)t * B_N + b) * C_N + c0] = o;
    }
}

extern "C" void kernel_launch(void* const* d_in, const int* in_sizes, int n_in,
                              void* d_out, int out_size, void* d_ws, size_t ws_size,
                              hipStream_t stream) {
    const float*   x    = (const float*)d_in[0];
    const uint8_t* mask = (const uint8_t*)d_in[1];
    const int*     tl   = (const int*)d_in[2];
    const float*   W    = (const float*)d_in[3];
    const float*   bo   = (const float*)d_in[4];
    float* out = (float*)d_out;
    float* ws  = (float*)d_ws;

    k_front <<<16, 256, 0, stream>>>(x, mask, tl, ws, out + (size_t)T_M * B_N * C_N);
    k_gather<<<dim3(T_M, B_N), 256, 0, stream>>>(x, ws);
    k_gemm  <<<dim3(128, 8), 256, 0, stream>>>(ws, W, bo, out);
}

// Round 3
// 275.108 us; speedup vs baseline: 1.8194x; 1.0855x over previous
//
#include <hip/hip_runtime.h>
#include <cstdint>
#include <cmath>

#define S_LEN 4096
#define B_N   16
#define C_N   512
#define CM1   511
#define T_M   512

// ws layout (float-unit offsets)
#define OFF_LW    65536     // fp32 [B][S]
#define OFF_RW    131072    // fp32 [B][S]
#define OFF_DEST  196640    // int  [B][S+1] = 16*4097
#define OFF_FEATS 262208    // bf16 [8192][512]  (occupies 2097152 float slots)
#define OFF_WB    2359360   // bf16 [512][512]   (occupies 131072 float slots)

__device__ __forceinline__ unsigned short f2bf(float f) {   // round-to-nearest-even
    unsigned u = __float_as_uint(f);
    return (unsigned short)((u + 0x7fffu + ((u >> 16) & 1u)) >> 16);
}

// ---------------- K_front: sigmoid + alpha_sum + scale + parallel scan ----------------
__global__ __launch_bounds__(256) void k_front(const float* __restrict__ x,
                                               const uint8_t* __restrict__ mask,
                                               const int* __restrict__ tl,
                                               float* __restrict__ ws,
                                               float* __restrict__ out_asum) {
    int b = blockIdx.x;
    int t = threadIdx.x;
    int lane = t & 63, wid = t >> 6;
    int s0 = t * 16;

    __shared__ float ssum[4];
    __shared__ float wsum[4];
    __shared__ float linc[256];

    float a[16];
    #pragma unroll
    for (int i = 0; i < 16; ++i) {
        int s = s0 + i;
        float v = x[((size_t)s * B_N + b) * C_N + CM1];
        if (mask[(size_t)b * S_LEN + s]) v = -10000.0f;
        a[i] = 1.0f / (1.0f + expf(-v));
    }

    float ls = 0.0f;
    #pragma unroll
    for (int i = 0; i < 16; ++i) ls += a[i];
    #pragma unroll
    for (int off = 32; off >= 1; off >>= 1) ls += __shfl_xor(ls, off, 64);
    if (lane == 0) ssum[wid] = ls;
    __syncthreads();
    float tot = (ssum[0] + ssum[1]) + (ssum[2] + ssum[3]);
    if (t == 0) out_asum[b] = tot;

    float tlf = (float)tl[b];
    #pragma unroll
    for (int i = 0; i < 16; ++i) a[i] = (a[i] * tlf) / tot;

    float p[16];
    float run = 0.0f;
    #pragma unroll
    for (int i = 0; i < 16; ++i) { run += a[i]; p[i] = run; }

    float sc = run;
    #pragma unroll
    for (int off = 1; off < 64; off <<= 1) {
        float v = __shfl_up(sc, off, 64);
        if (lane >= off) sc += v;
    }
    if (lane == 63) wsum[wid] = sc;
    __syncthreads();
    float woff = 0.0f;
    for (int w = 0; w < wid; ++w) woff += wsum[w];
    float excl = woff + (sc - run);

    linc[t] = excl + p[15];
    __syncthreads();
    float dsrc = (t == 0) ? 0.0f : linc[t - 1];
    int dprev = (int)floorf(dsrc + 1e-4f);

    float* lw   = ws + OFF_LW + (size_t)b * S_LEN;
    float* rw   = ws + OFF_RW + (size_t)b * S_LEN;
    int*   dest = (int*)(ws + OFF_DEST) + b * 4097;
    if (t == 0) dest[0] = 0;

    float lwv[16], rwv[16];
    int dnv[16];
    #pragma unroll
    for (int i = 0; i < 16; ++i) {
        float c  = excl + p[i];
        int   dn = (int)floorf(c + 1e-4f);
        int fire = dn - dprev;
        float rv = (fire > 0) ? (c - (float)dn) : a[i];
        float ex = (fire > 1) ? (float)(fire - 1) : 0.0f;
        lwv[i] = (a[i] - rv) - ex;
        rwv[i] = rv;
        dnv[i] = dn;
        dprev = dn;
    }
    #pragma unroll
    for (int q = 0; q < 4; ++q) {
        *(float4*)&lw[s0 + q * 4] = make_float4(lwv[q*4+0], lwv[q*4+1], lwv[q*4+2], lwv[q*4+3]);
        *(float4*)&rw[s0 + q * 4] = make_float4(rwv[q*4+0], rwv[q*4+1], rwv[q*4+2], rwv[q*4+3]);
    }
    #pragma unroll
    for (int i = 0; i < 16; ++i) dest[s0 + i + 1] = dnv[i];
}

// ---------------- K_wconv: W [512][511] fp32 -> Wb [512][512] bf16 (k padded) --------
__global__ __launch_bounds__(256) void k_wconv(const float* __restrict__ W,
                                               float* __restrict__ ws) {
    int g = blockIdx.x * 256 + threadIdx.x;   // 0..65535
    int n  = g >> 7;
    int kq = (g & 127) * 4;
    float v[4];
    #pragma unroll
    for (int j = 0; j < 4; ++j) {
        int k = kq + j;
        v[j] = (k < CM1) ? W[(size_t)n * CM1 + k] : 0.0f;
    }
    ushort4 o;
    o.x = f2bf(v[0]); o.y = f2bf(v[1]); o.z = f2bf(v[2]); o.w = f2bf(v[3]);
    unsigned short* Wb = (unsigned short*)(ws + OFF_WB);
    *(ushort4*)&Wb[(size_t)n * 512 + kq] = o;
}

// ---------------- K_gather: feats[b,t,:] = sum_s w(s,t)*x[s,b,0:511], bf16 out -------
// 2 t-rows per block (one per 128-lane half), float4 channel loads.
__global__ __launch_bounds__(256) void k_gather(const float* __restrict__ x,
                                                float* __restrict__ ws) {
    int sub = threadIdx.x >> 7;
    int l   = threadIdx.x & 127;
    int t = blockIdx.x * 2 + sub;
    int b = blockIdx.y;
    const int*   db = (const int*)(ws + OFF_DEST) + b * 4097;
    const float* lw = ws + OFF_LW + (size_t)b * S_LEN;
    const float* rw = ws + OFF_RW + (size_t)b * S_LEN;

    // s_hi: last s in [0,4095] with db[s] <= t
    int lo = 0, hi = 4097;
    while (lo < hi) {
        int mid = (lo + hi) >> 1;
        int v = (mid <= 4096) ? db[mid] : 0x7fffffff;
        if (v > t) hi = mid; else lo = mid + 1;
    }
    int s_hi = lo - 1; if (s_hi > 4095) s_hi = 4095;
    // s_lo: first s with db[s+1] >= t
    lo = 1; hi = 4097;
    while (lo < hi) {
        int mid = (lo + hi) >> 1;
        int v = (mid <= 4096) ? db[mid] : 0x7fffffff;
        if (v >= t) hi = mid; else lo = mid + 1;
    }
    int s_lo = lo - 1;

    float4 acc = make_float4(0.0f, 0.0f, 0.0f, 0.0f);
    const float4* x4 = (const float4*)x;
    for (int s = s_lo; s <= s_hi; ++s) {
        int ds = db[s], dn = db[s + 1];
        float w;
        if (t == ds)      w = (t == dn) ? (lw[s] + rw[s]) : lw[s];
        else              w = (t == dn) ? rw[s] : 1.0f;
        float4 xv = x4[((size_t)s * B_N + b) * 128 + l];
        acc.x += w * xv.x; acc.y += w * xv.y; acc.z += w * xv.z; acc.w += w * xv.w;
    }
    if (l == 127) acc.w = 0.0f;    // channel 511 excluded (K zero-pad)
    ushort4 o;
    o.x = f2bf(acc.x); o.y = f2bf(acc.y); o.z = f2bf(acc.z); o.w = f2bf(acc.w);
    unsigned short* feats = (unsigned short*)(ws + OFF_FEATS);
    *(ushort4*)&feats[(size_t)(b * T_M + t) * 512 + l * 4] = o;
}

// ---------------- K_mfma: out[t,b,:] = feats @ Wb^T + b_out (bf16 MFMA) --------------
// BM=128 BN=64 BK=64, grid (64,8)=512 blocks, 4 waves in 2x2, wave tile 64x32.
// LDS k-panel layout [p][m][8bf16]: staging writes contiguous, frag reads 2-way-alias free.
typedef __attribute__((ext_vector_type(8))) short bf16x8;
typedef __attribute__((ext_vector_type(4))) float f32x4;

__global__ __launch_bounds__(256) void k_mfma(const float* __restrict__ ws,
                                              const float* __restrict__ bo,
                                              float* __restrict__ out) {
    __shared__ uint4 Asl[8 * 128];   // 16 KB
    __shared__ uint4 Bsl[8 * 64];    // 8 KB
    const uint4* feats4 = (const uint4*)(ws + OFF_FEATS);
    const uint4* Wb4    = (const uint4*)(ws + OFF_WB);
    int tid  = threadIdx.x;
    int lane = tid & 63;
    int wv   = tid >> 6;
    int wm   = wv >> 1, wn = wv & 1;
    int quad = lane >> 4, r16 = lane & 15;
    int m0 = blockIdx.x * 128;
    int n0 = blockIdx.y * 64;

    f32x4 acc[4][2] = {};
    for (int k0 = 0; k0 < 512; k0 += 64) {
        __syncthreads();
        int kp = k0 >> 3;
        #pragma unroll
        for (int i = 0; i < 4; ++i) {
            int e = i * 256 + tid;
            int p = e & 7, m = e >> 3;
            Asl[p * 128 + m] = feats4[(size_t)(m0 + m) * 64 + kp + p];
        }
        #pragma unroll
        for (int i = 0; i < 2; ++i) {
            int e = i * 256 + tid;
            int p = e & 7, n = e >> 3;
            Bsl[p * 64 + n] = Wb4[(size_t)(n0 + n) * 64 + kp + p];
        }
        __syncthreads();
        #pragma unroll
        for (int kk = 0; kk < 2; ++kk) {
            bf16x8 af[4], bfr[2];
            #pragma unroll
            for (int mt = 0; mt < 4; ++mt)
                af[mt] = *(const bf16x8*)&Asl[(kk * 4 + quad) * 128 + wm * 64 + mt * 16 + r16];
            #pragma unroll
            for (int nt = 0; nt < 2; ++nt)
                bfr[nt] = *(const bf16x8*)&Bsl[(kk * 4 + quad) * 64 + wn * 32 + nt * 16 + r16];
            #pragma unroll
            for (int mt = 0; mt < 4; ++mt)
                #pragma unroll
                for (int nt = 0; nt < 2; ++nt)
                    acc[mt][nt] = __builtin_amdgcn_mfma_f32_16x16x32_bf16(af[mt], bfr[nt], acc[mt][nt], 0, 0, 0);
        }
    }
    #pragma unroll
    for (int nt = 0; nt < 2; ++nt) {
        int n = n0 + wn * 32 + nt * 16 + r16;
        float bias = bo[n];
        #pragma unroll
        for (int mt = 0; mt < 4; ++mt) {
            #pragma unroll
            for (int r = 0; r < 4; ++r) {
                int m = m0 + wm * 64 + mt * 16 + quad * 4 + r;
                int t = m & 511, b = m >> 9;
                out[((size_t)t * B_N + b) * C_N + n] = acc[mt][nt][r] + bias;
            }
        }
    }
}

extern "C" void kernel_launch(void* const* d_in, const int* in_sizes, int n_in,
                              void* d_out, int out_size, void* d_ws, size_t ws_size,
                              hipStream_t stream) {
    const float*   x    = (const float*)d_in[0];
    const uint8_t* mask = (const uint8_t*)d_in[1];
    const int*     tl   = (const int*)d_in[2];
    const float*   W    = (const float*)d_in[3];
    const float*   bo   = (const float*)d_in[4];
    float* out = (float*)d_out;
    float* ws  = (float*)d_ws;

    k_front <<<16, 256, 0, stream>>>(x, mask, tl, ws, out + (size_t)T_M * B_N * C_N);
    k_wconv <<<256, 256, 0, stream>>>(W, ws);
    k_gather<<<dim3(256, B_N), 256, 0, stream>>>(x, ws);
    k_mfma  <<<dim3(64, 8), 256, 0, stream>>>(ws, bo, out);
}